// Round 3
// baseline (581.428 us; speedup 1.0000x reference)
//
#include <hip/hip_runtime.h>

// ---------------------------------------------------------------------------
// SortNet: 3-layer 1x1-conv MLP (64->64->16->1) with training-mode BatchNorm
// + ReLU, per-batch top-64 over N, gather of input + score.
//
// Register-resident GEMM structure (no LDS staging, no barriers in hot loops):
// weights are wave-uniform (s_load / scalar cache), activations per-lane.
//
// Pipeline (9 launches + 1 memset, all deterministic):
//   k_prep     : transpose w0 (64x64) and w1 (16x64)
//   k_stat0    : y0 = w0@sv + b0 (32 ch/thread, 2-way split), sum/sumsq partials
//   k_reduce0  : finalize scale0/shift0
//   k_layer01  : recompute y0 (64 ch/thread), bn0+relu, y1 = w1@h0 + b1,
//                write y1, stats1 partials
//   k_reduce1  : finalize scale1/shift1
//   k_layer2   : y2 = w2@relu(bn1(y1)) + b2, stats2 partials, per-batch
//                4096-bin key histogram (radix-select pass 1)
//   k_thresh   : per batch, threshold bin T with count(bin >= T) >= 64
//   k_compact  : compact keys with bin >= T (~64-130 candidates) via atomics
//   k_final    : 1 wave/batch: 64 rounds of in-register wave argmax
//                (jax tie-break), stats2 finalize, score decode, gather.
// ---------------------------------------------------------------------------

constexpr int   B_   = 16;
constexpr int   N_   = 32768;
constexpr int   K_   = 64;            // TOP_K
constexpr long long S_ = (long long)B_ * N_;   // 524288
constexpr float EPS_ = 1e-5f;

constexpr int NBA   = 512;    // k_stat0 blocks: 256 position-blocks x 2 halves
constexpr int PA_POS = 8;     // positions per thread in k_stat0
constexpr int NB1   = 2048;   // k_layer01 blocks (1 position per thread)
constexpr int NB2   = 256;    // k_layer2 blocks (2048 pos each)
constexpr int NBC   = 128;    // k_compact blocks (4096 pos each)
constexpr int NBINS = 4096;   // radix-select bins (key >> 20)
constexpr int CAP   = 1024;   // candidate capacity per batch

__device__ __forceinline__ unsigned key_map(float f) {
  unsigned u = __float_as_uint(f);
  return (u & 0x80000000u) ? ~u : (u | 0x80000000u);
}

// --------------------------- k_prep ----------------------------------------
__global__ __launch_bounds__(256) void k_prep(const float* __restrict__ w0,
                                              const float* __restrict__ w1,
                                              float* __restrict__ w0T,
                                              float* __restrict__ w1T) {
  int t = threadIdx.x;
  for (int e = t; e < 64 * 64; e += 256) {
    int o = e >> 6, f = e & 63;
    w0T[f * 64 + o] = w0[e];          // w0T[f][o] = w0[o][f]
  }
  for (int e = t; e < 16 * 64; e += 256) {
    int o = e >> 6, c = e & 63;
    w1T[c * 16 + o] = w1[e];          // w1T[c][o] = w1[o][c]
  }
}

// --------------------------- k_stat0 ---------------------------------------
// blk = pb*2 + half; thread handles PA_POS positions x 32 channels.
// Per f: 1 coalesced dword load + 32 FMA from scalar-cached weights.
__global__ __launch_bounds__(256) void k_stat0(const float* __restrict__ sv,
                                               const float* __restrict__ w0T,
                                               const float* __restrict__ b0,
                                               float* __restrict__ p0) {
  __shared__ float red[4][64];
  const int t    = threadIdx.x;
  const int blk  = blockIdx.x;
  const int half = blk & 1;
  const int pb   = blk >> 1;            // 0..255, 2048 positions each
  const int c0   = half * 32;

  float bb[32];
#pragma unroll
  for (int c = 0; c < 32; ++c) bb[c] = b0[c0 + c];

  float s1[32], s2[32];
#pragma unroll
  for (int c = 0; c < 32; ++c) { s1[c] = 0.f; s2[c] = 0.f; }

  const long long pbase = (long long)pb * 2048 + t;
  for (int i = 0; i < PA_POS; ++i) {
    const long long pos = pbase + i * 256;
    const int b = (int)(pos >> 15);
    const int n = (int)(pos & (N_ - 1));
    const float* xp = sv + ((long long)b * 64) * N_ + n;
    float y[32];
#pragma unroll
    for (int c = 0; c < 32; ++c) y[c] = bb[c];
#pragma unroll
    for (int f = 0; f < 64; ++f) {
      float x = xp[(long long)f * N_];
      const float* wr = w0T + f * 64 + c0;    // wave-uniform -> s_load
#pragma unroll
      for (int c = 0; c < 32; ++c) y[c] = fmaf(wr[c], x, y[c]);
    }
#pragma unroll
    for (int c = 0; c < 32; ++c) {
      s1[c] += y[c];
      s2[c] = fmaf(y[c], y[c], s2[c]);
    }
  }

#pragma unroll
  for (int c = 0; c < 32; ++c) {
#pragma unroll
    for (int off = 32; off; off >>= 1) {
      s1[c] += __shfl_down(s1[c], off, 64);
      s2[c] += __shfl_down(s2[c], off, 64);
    }
  }
  const int wid = t >> 6, lid = t & 63;
  if (lid == 0) {
#pragma unroll
    for (int c = 0; c < 32; ++c) { red[wid][c] = s1[c]; red[wid][32 + c] = s2[c]; }
  }
  __syncthreads();
  if (t < 64)
    p0[blk * 64 + t] = (red[0][t] + red[1][t]) + (red[2][t] + red[3][t]);
}

// --------------------------- k_reduce0 -------------------------------------
// p0[blk][0:32]=s1, [32:64]=s2 for channels (blk&1)*32 + c.
__global__ __launch_bounds__(128) void k_reduce0(const float* __restrict__ p0,
                                                 const float* __restrict__ g,
                                                 const float* __restrict__ bt,
                                                 float* __restrict__ st) {
  __shared__ float l[128];
  const int j    = threadIdx.x;       // j = stat*64 + ch
  const int stat = j >> 6;
  const int ch   = j & 63;
  const int half = ch >> 5, c = ch & 31;
  float a = 0.f;
  for (int pb = 0; pb < 256; ++pb)
    a += p0[(pb * 2 + half) * 64 + stat * 32 + c];
  l[j] = a;
  __syncthreads();
  if (j < 64) {
    const float inv = 1.f / (float)S_;
    float mean = l[j] * inv;
    float ex2  = l[64 + j] * inv;
    float var  = ex2 - mean * mean;
    float sc   = g[j] * rsqrtf(var + EPS_);
    st[j]      = sc;
    st[64 + j] = bt[j] - mean * sc;
  }
}

// --------------------------- k_layer01 -------------------------------------
// 1 position per thread, all 64 channels in registers. conv0 (4096 FMA) ->
// bn0+relu -> conv1 (1024 FMA) -> coalesced y1 stores + stats1 partials.
__global__ __launch_bounds__(256) void k_layer01(const float* __restrict__ sv,
                                                 const float* __restrict__ w0T,
                                                 const float* __restrict__ b0,
                                                 const float* __restrict__ st0,
                                                 const float* __restrict__ w1T,
                                                 const float* __restrict__ b1,
                                                 float* __restrict__ y1,
                                                 float* __restrict__ p1) {
  __shared__ float red[4][32];
  const int t   = threadIdx.x;
  const int blk = blockIdx.x;
  const long long pos = (long long)blk * 256 + t;
  const int b = (int)(pos >> 15);
  const int n = (int)(pos & (N_ - 1));
  const float* xp = sv + ((long long)b * 64) * N_ + n;

  float y[64];
#pragma unroll
  for (int c = 0; c < 64; ++c) y[c] = b0[c];
#pragma unroll
  for (int f = 0; f < 64; ++f) {
    float x = xp[(long long)f * N_];
    const float* wr = w0T + f * 64;           // wave-uniform -> s_load
#pragma unroll
    for (int c = 0; c < 64; ++c) y[c] = fmaf(wr[c], x, y[c]);
  }
#pragma unroll
  for (int c = 0; c < 64; ++c) {
    float h = fmaf(y[c], st0[c], st0[64 + c]);
    y[c] = h > 0.f ? h : 0.f;
  }

  float z[16];
#pragma unroll
  for (int j = 0; j < 16; ++j) z[j] = b1[j];
#pragma unroll
  for (int f = 0; f < 64; ++f) {
    const float* wr = w1T + f * 16;           // wave-uniform -> s_load
#pragma unroll
    for (int j = 0; j < 16; ++j) z[j] = fmaf(wr[j], y[f], z[j]);
  }

  float* yo = y1 + ((long long)b * 16) * N_ + n;
#pragma unroll
  for (int j = 0; j < 16; ++j) yo[(long long)j * N_] = z[j];

  const int wid = t >> 6, lid = t & 63;
#pragma unroll
  for (int j = 0; j < 16; ++j) {
    float a = z[j], q = z[j] * z[j];
#pragma unroll
    for (int off = 32; off; off >>= 1) {
      a += __shfl_down(a, off, 64);
      q += __shfl_down(q, off, 64);
    }
    if (lid == 0) { red[wid][j] = a; red[wid][16 + j] = q; }
  }
  __syncthreads();
  if (t < 32)
    p1[blk * 32 + t] = (red[0][t] + red[1][t]) + (red[2][t] + red[3][t]);
}

// --------------------------- k_reduce1 -------------------------------------
__global__ __launch_bounds__(64) void k_reduce1(const float* __restrict__ p1,
                                                const float* __restrict__ g,
                                                const float* __restrict__ bt,
                                                float* __restrict__ st) {
  __shared__ float l[32];
  int j = threadIdx.x;
  if (j < 32) {
    float a0 = 0.f, a1 = 0.f, a2 = 0.f, a3 = 0.f;
    for (int i = 0; i < NB1; i += 4) {
      a0 += p1[(long long)(i + 0) * 32 + j];
      a1 += p1[(long long)(i + 1) * 32 + j];
      a2 += p1[(long long)(i + 2) * 32 + j];
      a3 += p1[(long long)(i + 3) * 32 + j];
    }
    l[j] = (a0 + a1) + (a2 + a3);
  }
  __syncthreads();
  if (j < 16) {
    const float inv = 1.f / (float)S_;
    float mean = l[j] * inv;
    float ex2  = l[16 + j] * inv;
    float var  = ex2 - mean * mean;
    float sc   = g[j] * rsqrtf(var + EPS_);
    st[j]      = sc;
    st[16 + j] = bt[j] - mean * sc;
  }
}

// --------------------------- k_layer2 --------------------------------------
// 256 blocks x 1024 threads; 2 consecutive positions per thread (float2).
__global__ __launch_bounds__(1024) void k_layer2(const float* __restrict__ y1,
                                                 const float* __restrict__ st1,
                                                 const float* __restrict__ w2,
                                                 const float* __restrict__ b2,
                                                 float* __restrict__ y2,
                                                 float* __restrict__ p2,
                                                 int* __restrict__ ghist) {
  __shared__ int hist[NBINS];
  __shared__ float ls[16], lq[16];
  const int t   = threadIdx.x;
  const int blk = blockIdx.x;
  const int b   = blk >> 4;
  const int n0  = ((blk & 15) << 11) | (t << 1);   // 2048 positions per block

#pragma unroll
  for (int i = 0; i < NBINS / 1024; ++i) hist[t + i * 1024] = 0;

  float sc[16], sh[16], w[16];
#pragma unroll
  for (int c = 0; c < 16; ++c) { sc[c] = st1[c]; sh[c] = st1[16 + c]; w[c] = w2[c]; }
  const float bias = b2[0];

  float a0 = bias, a1 = bias;
  const float* base = y1 + ((long long)b * 16) * N_ + n0;
#pragma unroll
  for (int c = 0; c < 16; ++c) {
    float2 v = *(const float2*)(base + (long long)c * N_);
    float h;
    h = fmaf(v.x, sc[c], sh[c]); h = h > 0.f ? h : 0.f; a0 = fmaf(w[c], h, a0);
    h = fmaf(v.y, sc[c], sh[c]); h = h > 0.f ? h : 0.f; a1 = fmaf(w[c], h, a1);
  }
  float2 o; o.x = a0; o.y = a1;
  *(float2*)(y2 + (long long)b * N_ + n0) = o;

  __syncthreads();   // hist zeroed before any atomic

  atomicAdd(&hist[key_map(a0) >> 20], 1);
  atomicAdd(&hist[key_map(a1) >> 20], 1);

  float ss = a0 + a1;
  float sq = fmaf(a0, a0, a1 * a1);
#pragma unroll
  for (int off = 32; off; off >>= 1) {
    ss += __shfl_down(ss, off, 64);
    sq += __shfl_down(sq, off, 64);
  }
  const int wid = t >> 6, lid = t & 63;
  if (lid == 0) { ls[wid] = ss; lq[wid] = sq; }
  __syncthreads();   // covers ls/lq stores AND hist atomics
  if (t == 0) {
    float Sv = 0.f, Qv = 0.f;
#pragma unroll
    for (int i = 0; i < 16; ++i) { Sv += ls[i]; Qv += lq[i]; }
    p2[blk * 2 + 0] = Sv;
    p2[blk * 2 + 1] = Qv;
  }
#pragma unroll
  for (int i = 0; i < NBINS / 1024; ++i) {
    int v = hist[t + i * 1024];
    if (v) atomicAdd(&ghist[b * NBINS + t + i * 1024], v);
  }
}

// --------------------------- k_thresh --------------------------------------
__global__ __launch_bounds__(256) void k_thresh(const int* __restrict__ ghist,
                                                int* __restrict__ Tb) {
  __shared__ int hl[NBINS + NBINS / 64];
  const int t = threadIdx.x, b = blockIdx.x;
  const int* h = ghist + b * NBINS;
  for (int i = t; i < NBINS; i += 256) hl[i + (i >> 6)] = h[i];
  __syncthreads();
  if (t < 64) {
    const int l = t;
    int s = 0;
    for (int j = 0; j < 64; ++j) s += hl[(l * 64 + j) + l];
    int Sv = s;
#pragma unroll
    for (int off = 1; off < 64; off <<= 1) {
      int v = __shfl_down(Sv, off, 64);
      if (l + off < 64) Sv += v;
    }
    unsigned long long m = __ballot(Sv >= K_);
    const int lstar = 63 - __builtin_clzll(m);
    const int tailS = (lstar < 63) ? __shfl(Sv, lstar + 1, 64) : 0;
    int Tj = hl[(lstar * 64 + l) + lstar];
#pragma unroll
    for (int off = 1; off < 64; off <<= 1) {
      int v = __shfl_down(Tj, off, 64);
      if (l + off < 64) Tj += v;
    }
    const int cge = Tj + tailS;
    unsigned long long m2 = __ballot(cge >= K_);
    const int jstar = 63 - __builtin_clzll(m2);
    if (l == 0) Tb[b] = lstar * 64 + jstar;
  }
}

// --------------------------- k_compact -------------------------------------
__global__ __launch_bounds__(1024) void k_compact(const float* __restrict__ y2,
                                                  const int* __restrict__ Tb,
                                                  int* __restrict__ cnt,
                                                  unsigned long long* __restrict__ cand) {
  const int t = threadIdx.x, blk = blockIdx.x;
  const int b  = blk >> 3;
  const int n0 = ((blk & 7) << 12) | (t << 2);
  const int T  = Tb[b];
  float4 v = *(const float4*)(y2 + (long long)b * N_ + n0);
  unsigned long long* cb = cand + (long long)b * CAP;
#define DO_CAND(comp, off)                                                    \
  {                                                                           \
    unsigned u = key_map(comp);                                               \
    if ((int)(u >> 20) >= T) {                                                \
      int slot = atomicAdd(&cnt[b], 1);                                       \
      if (slot < CAP)                                                         \
        cb[slot] = ((unsigned long long)u << 32) |                            \
                   (unsigned)(N_ - 1 - (n0 + off));                           \
    }                                                                         \
  }
  DO_CAND(v.x, 0) DO_CAND(v.y, 1) DO_CAND(v.z, 2) DO_CAND(v.w, 3)
#undef DO_CAND
}

// --------------------------- k_final ---------------------------------------
__global__ __launch_bounds__(64) void k_final(const unsigned long long* __restrict__ cand,
                                              const int* __restrict__ cnt,
                                              const float* __restrict__ p2,
                                              const float* __restrict__ g2,
                                              const float* __restrict__ bt2,
                                              const float* __restrict__ inp,
                                              float* __restrict__ out) {
  const int b = blockIdx.x, l = threadIdx.x;

  // stats2 from 256 block partials (fixed-order tree, same in all blocks)
  float s1 = (p2[2 * l] + p2[2 * (l + 64)]) +
             (p2[2 * (l + 128)] + p2[2 * (l + 192)]);
  float q1 = (p2[2 * l + 1] + p2[2 * (l + 64) + 1]) +
             (p2[2 * (l + 128) + 1] + p2[2 * (l + 192) + 1]);
#pragma unroll
  for (int off = 32; off; off >>= 1) {
    s1 += __shfl_down(s1, off, 64);
    q1 += __shfl_down(q1, off, 64);
  }
  s1 = __shfl(s1, 0, 64);
  q1 = __shfl(q1, 0, 64);
  const float inv = 1.f / (float)S_;
  const float mean = s1 * inv;
  const float var  = q1 * inv - mean * mean;
  const float scale2 = g2[0] * rsqrtf(var + EPS_);
  const float shift2 = bt2[0] - mean * scale2;

  int cn = cnt[b];
  if (cn > CAP) cn = CAP;
  const unsigned long long* cb = cand + (long long)b * CAP;
  unsigned long long k[16];
#pragma unroll
  for (int r = 0; r < 16; ++r) {
    int i = l + r * 64;
    k[r] = (i < cn) ? cb[i] : 0ull;
  }
  unsigned long long cur = 0ull;
#pragma unroll
  for (int r = 0; r < 16; ++r) cur = k[r] > cur ? k[r] : cur;

  int myidx = 0;
  unsigned mymap = 0;
  for (int r = 0; r < K_; ++r) {
    unsigned long long m = cur;
#pragma unroll
    for (int off = 32; off; off >>= 1) {
      unsigned long long o = __shfl_xor(m, off, 64);
      m = o > m ? o : m;
    }
    if (r == l) {
      myidx = N_ - 1 - (int)(m & 0xffffffffu);
      mymap = (unsigned)(m >> 32);
    }
    if (cur == m) {          // exactly one lane (keys unique)
#pragma unroll
      for (int r2 = 0; r2 < 16; ++r2)
        if (k[r2] == m) k[r2] = 0ull;
      unsigned long long c2 = 0ull;
#pragma unroll
      for (int r2 = 0; r2 < 16; ++r2) c2 = k[r2] > c2 ? k[r2] : c2;
      cur = c2;
    }
  }

  unsigned u = mymap;
  u = (u & 0x80000000u) ? (u & 0x7fffffffu) : ~u;
  float v = __uint_as_float(u);
  float scv = fmaf(v, scale2, shift2);
  scv = scv > 0.f ? scv : 0.f;

  const float* ib = inp + ((long long)b * 64) * N_;
#pragma unroll 4
  for (int f = 0; f < 64; ++f)
    out[((long long)b * 65 + f) * 64 + l] = ib[(long long)f * N_ + myidx];
  out[((long long)b * 65 + 64) * 64 + l] = scv;
  out[(long long)B_ * 65 * 64 + b * 64 + l] = (float)myidx;
}

// --------------------------- launch ----------------------------------------
extern "C" void kernel_launch(void* const* d_in, const int* in_sizes, int n_in,
                              void* d_out, int out_size, void* d_ws, size_t ws_size,
                              hipStream_t stream) {
  const float* sv  = (const float*)d_in[0];
  const float* inp = (const float*)d_in[1];
  const float* w0  = (const float*)d_in[2];
  const float* b0  = (const float*)d_in[3];
  const float* w1  = (const float*)d_in[4];
  const float* b1  = (const float*)d_in[5];
  const float* w2  = (const float*)d_in[6];
  const float* b2  = (const float*)d_in[7];
  const float* g0  = (const float*)d_in[8];
  const float* bt0 = (const float*)d_in[9];
  const float* g1  = (const float*)d_in[10];
  const float* bt1 = (const float*)d_in[11];
  const float* g2  = (const float*)d_in[12];
  const float* bt2 = (const float*)d_in[13];
  float* out = (float*)d_out;

  float* ws  = (float*)d_ws;
  float* y1  = ws;                                    // 8388608 floats
  float* y2  = y1 + (size_t)S_ * 16;                  //  524288
  float* p0  = y2 + (size_t)S_;                       //  NBA*64 = 32768
  float* p1  = p0 + (size_t)NBA * 64;                 //  NB1*32 = 65536
  float* p2  = p1 + (size_t)NB1 * 32;                 //  NB2*2  = 512
  float* st0 = p2 + (size_t)NB2 * 2;                  //  128
  float* st1 = st0 + 128;                             //  32
  float* w0T = st1 + 32;                              //  4096
  float* w1T = w0T + 4096;                            //  1024
  int*   ghist = (int*)(w1T + 1024);                  //  B*NBINS = 65536 ints
  int*   cnt   = ghist + (size_t)B_ * NBINS;          //  16 ints
  int*   Tb    = cnt + 16;                            //  16 ints
  unsigned long long* cand =
      (unsigned long long*)(Tb + 16);                 //  16*CAP u64

  hipMemsetAsync(ghist, 0, ((size_t)B_ * NBINS + 16) * sizeof(int), stream);

  k_prep   <<<1,    256, 0, stream>>>(w0, w1, w0T, w1T);
  k_stat0  <<<NBA,  256, 0, stream>>>(sv, w0T, b0, p0);
  k_reduce0<<<1,    128, 0, stream>>>(p0, g0, bt0, st0);
  k_layer01<<<NB1,  256, 0, stream>>>(sv, w0T, b0, st0, w1T, b1, y1, p1);
  k_reduce1<<<1,     64, 0, stream>>>(p1, g1, bt1, st1);
  k_layer2 <<<NB2, 1024, 0, stream>>>(y1, st1, w2, b2, y2, p2, ghist);
  k_thresh <<<B_,   256, 0, stream>>>(ghist, Tb);
  k_compact<<<NBC, 1024, 0, stream>>>(y2, Tb, cnt, cand);
  k_final  <<<B_,    64, 0, stream>>>(cand, cnt, p2, g2, bt2, inp, out);
}